// Round 16
// baseline (510.612 us; speedup 1.0000x reference)
//
#include <hip/hip_runtime.h>
#include <hip/hip_bf16.h>
#include <float.h>

#define NN 200000
#define NE 400000
#define NG 4096
#define FIN 77
#define DD 128
#define BN_EPS 1e-5f
#define NB_SCAN ((NN + 255) / 256)   // 782
#define NBLK (NN / 64)               // 3125 64-row tiles
#define PGRID 1024                   // persistent blocks: 4/CU x 256 CU
#define WCAP 1024                    // LDS slot-window capacity

// prep role ranges
#define GS_BLKS 17
#define CNT_BLKS ((NE + 255) / 256)  // 1563
#define XCONV_BLKS (NN * 12 / 256)   // 9375
#define WCONV_BLKS 192

typedef float f32x4 __attribute__((ext_vector_type(4)));
typedef short s16x8 __attribute__((ext_vector_type(8)));

__device__ __forceinline__ unsigned short f2bf(float x) {
    unsigned b = __float_as_uint(x);
    unsigned r = (b + 0x7FFFu + ((b >> 16) & 1u)) >> 16;
    return (unsigned short)r;
}
__device__ __forceinline__ float bf2f(unsigned short u) {
    return __uint_as_float(((unsigned)u) << 16);
}

__device__ __forceinline__ int load_idx(const void* p, int is64, long long i) {
    return is64 ? (int)((const long long*)p)[i] : ((const int*)p)[i];
}

// ---------- prep: graph_starts + degree count + xconv + wconv + detect (one launch) ----------
__global__ __launch_bounds__(256) void prep_kernel(
    const float* __restrict__ x, unsigned short* __restrict__ xb,
    const float* __restrict__ w10, const float* __restrict__ w20,
    const float* __restrict__ w11, const float* __restrict__ w21,
    const float* __restrict__ w12, const float* __restrict__ w22,
    unsigned short* __restrict__ wtb,
    const void* __restrict__ eidx, const void* __restrict__ batch,
    int* __restrict__ start, int* __restrict__ deg, int* __restrict__ flags)
{
    int b = blockIdx.x;
    if (b < GS_BLKS) {
        __shared__ int sb64;
        if (threadIdx.x == 0) {
            int b64 = 1;
            const unsigned* bw = (const unsigned*)batch;
            for (int i = 0; i < 16; i++) if (bw[NN - 1 - 2 * i] != 0u) b64 = 0;
            sb64 = b64;
        }
        __syncthreads();
        int is64 = sb64;
        int g = b * 256 + threadIdx.x;
        if (g > NG) return;
        int lo = 0, hi = NN;
        while (lo < hi) {
            int mid = (lo + hi) >> 1;
            int v = load_idx(batch, is64, mid);
            if (v < g) lo = mid + 1; else hi = mid;
        }
        start[g] = lo;
    } else if (b < GS_BLKS + CNT_BLKS) {
        __shared__ int se64;
        if (threadIdx.x == 0) {
            int e64 = 1;
            const unsigned* ew = (const unsigned*)eidx;
            for (int i = 0; i < 16; i++) if (ew[2 * NE - 1 - 2 * i] != 0u) e64 = 0;
            se64 = e64;
        }
        __syncthreads();
        int e = (b - GS_BLKS) * 256 + threadIdx.x;
        if (e >= NE) return;
        int dst = load_idx(eidx, se64, (long long)NE + e);
        atomicAdd(&deg[dst], 1);
    } else if (b < GS_BLKS + CNT_BLKS + XCONV_BLKS) {
        int idx = (b - GS_BLKS - CNT_BLKS) * 256 + threadIdx.x;
        int row = idx / 12, c8 = (idx % 12) * 8;
        union { s16x8 v; unsigned short u[8]; } pk;
#pragma unroll
        for (int j = 0; j < 8; j++) {
            int c = c8 + j;
            pk.u[j] = (c < FIN) ? f2bf(x[(long long)row * FIN + c]) : (unsigned short)0;
        }
        *(s16x8*)&xb[(long long)row * 96 + c8] = pk.v;
    } else if (b < GS_BLKS + CNT_BLKS + XCONV_BLKS + WCONV_BLKS) {
        int bb = b - GS_BLKS - CNT_BLKS - XCONV_BLKS;
        int l = bb >> 6;
        int idx = (bb & 63) * 256 + threadIdx.x;
        int c = idx >> 7, k = idx & 127;
        const float* w1 = (l == 0) ? w10 : ((l == 1) ? w11 : w12);
        const float* w2 = (l == 0) ? w20 : ((l == 1) ? w21 : w22);
        int K1 = (l == 0) ? FIN : DD;
        unsigned short* wt1 = wtb + l * 2 * 16384;
        wt1[idx] = f2bf(k < K1 ? w1[k * DD + c] : 0.f);
        wt1[16384 + idx] = f2bf(w2[k * DD + c]);
    } else {
        if (threadIdx.x == 0) {
            int e64 = 1, b64 = 1;
            const unsigned* ew = (const unsigned*)eidx;
            const unsigned* bw = (const unsigned*)batch;
            for (int i = 0; i < 16; i++) {
                if (ew[2 * NE - 1 - 2 * i] != 0u) e64 = 0;
                if (bw[NN - 1 - 2 * i] != 0u) b64 = 0;
            }
            flags[0] = e64;
            flags[1] = b64;
        }
    }
}

__global__ void scan1_kernel(const int* __restrict__ deg, int* __restrict__ incl,
                             int* __restrict__ bsum) {
    __shared__ int sh[256];
    int i = blockIdx.x * 256 + threadIdx.x;
    int v = (i < NN) ? deg[i] : 0;
    sh[threadIdx.x] = v;
    __syncthreads();
    for (int off = 1; off < 256; off <<= 1) {
        int t = (threadIdx.x >= off) ? sh[threadIdx.x - off] : 0;
        __syncthreads();
        sh[threadIdx.x] += t;
        __syncthreads();
    }
    if (i < NN) incl[i] = sh[threadIdx.x];
    if (threadIdx.x == 255) bsum[blockIdx.x] = sh[255];
}

// scan2+scan3 merged: each block re-sums bsum[0..b) itself (<=782 ints, cheap)
__global__ __launch_bounds__(256) void scan23_kernel(
    const int* __restrict__ incl, const int* __restrict__ deg,
    const int* __restrict__ bsum, int* __restrict__ rowptr, int* __restrict__ cursor) {
    __shared__ int red[256];
    int b = blockIdx.x;
    int t = threadIdx.x;
    int s = 0;
    for (int i = t; i < b; i += 256) s += bsum[i];
    red[t] = s;
    __syncthreads();
    for (int off = 128; off > 0; off >>= 1) {
        if (t < off) red[t] += red[t + off];
        __syncthreads();
    }
    int pfx = red[0];
    int i = b * 256 + t;
    if (i < NN) {
        int ex = pfx + incl[i] - deg[i];
        rowptr[i] = ex;
        cursor[i] = ex;
    }
    if (i == 0) rowptr[NN] = NE;
}

__global__ void fill_kernel(const void* __restrict__ eidx, const int* __restrict__ flags,
                            int* __restrict__ cursor, int* __restrict__ slots) {
    int e = blockIdx.x * 256 + threadIdx.x;
    if (e >= NE) return;
    int is64 = flags[0];
    int src = load_idx(eidx, is64, e);
    int dst = load_idx(eidx, is64, (long long)NE + e);
    int pos = atomicAdd(&cursor[dst], 1);
    slots[pos] = src;
}

// ---------- fused layer (persistent): gather(+BN affine) -> GEMM1 -> GEMM2 -> h + partials ----------
// 1024 persistent blocks (4/CU) grid-stride over 3125 64-row tiles: kills the drain tail.
template <int L0>
__global__ __launch_bounds__(512, 8) void fused_layer(
    const unsigned short* __restrict__ src, const float* __restrict__ ss,
    const int* __restrict__ rowptr, const int* __restrict__ slots,
    const unsigned short* __restrict__ wt1, const unsigned short* __restrict__ wt2,
    const float* __restrict__ b1, const float* __restrict__ b2,
    unsigned short* __restrict__ out, float* __restrict__ partials)
{
    __shared__ unsigned short Xs[64 * 128];
    __shared__ int s_lo[65];
    __shared__ int s_win[WCAP];
    constexpr int SK = L0 ? 96 : 128;
    constexpr int KS1 = L0 ? 3 : 4;
    int tid = threadIdx.x;
    int lane = tid & 63;
    int w = tid >> 6;                 // 0..7
    int colbase = w * 16 + (lane & 15);

    for (int tile = blockIdx.x; tile < NBLK; tile += PGRID) {
        int rowBase = tile * 64;

        int wb = rowptr[rowBase];
        int wn = rowptr[rowBase + 64] - wb;
        if (tid < 65) s_lo[tid] = rowptr[rowBase + tid];
        int wcap = (wn < WCAP) ? wn : WCAP;
        for (int i = tid; i < wcap; i += 512) s_win[i] = slots[wb + i];
        __syncthreads();

        {
            int rp = tid >> 4;            // 0..31
            int c8 = (tid & 15) * 8;
            float sc[8], sh[8];
            if (!L0) {
#pragma unroll
                for (int j = 0; j < 8; j++) { sc[j] = ss[c8 + j]; sh[j] = ss[DD + c8 + j]; }
            }
            int rA = rp, rB = 32 + rp;
            int griA = rowBase + rA, griB = rowBase + rB;
            bool skip = (L0 && c8 >= 96);
            s16x8 voA = {}, v0A = {}, v1A = {}, voB = {}, v0B = {}, v1B = {};
            int dA = 0, dB = 0, loA = 0, loB = 0, oA = 0, oB = 0;
            float mA0 = 0.f, mA1 = 0.f, mB0 = 0.f, mB1 = 0.f;
            if (!skip) {
                loA = s_lo[rA]; dA = s_lo[rA + 1] - loA; oA = loA - wb;
                loB = s_lo[rB]; dB = s_lo[rB + 1] - loB; oB = loB - wb;
                int iA0 = (dA > 0) ? ((oA < WCAP) ? s_win[oA] : slots[loA]) : griA;
                int iA1 = (dA > 1) ? ((oA + 1 < WCAP) ? s_win[oA + 1] : slots[loA + 1]) : griA;
                int iB0 = (dB > 0) ? ((oB < WCAP) ? s_win[oB] : slots[loB]) : griB;
                int iB1 = (dB > 1) ? ((oB + 1 < WCAP) ? s_win[oB + 1] : slots[loB + 1]) : griB;
                voA = *(const s16x8*)&src[griA * SK + c8];
                v0A = *(const s16x8*)&src[iA0 * SK + c8];
                v1A = *(const s16x8*)&src[iA1 * SK + c8];
                voB = *(const s16x8*)&src[griB * SK + c8];
                v0B = *(const s16x8*)&src[iB0 * SK + c8];
                v1B = *(const s16x8*)&src[iB1 * SK + c8];
                mA0 = (dA > 0) ? 1.f : 0.f; mA1 = (dA > 1) ? 1.f : 0.f;
                mB0 = (dB > 0) ? 1.f : 0.f; mB1 = (dB > 1) ? 1.f : 0.f;
            }
            float aA[8], aB[8];
#pragma unroll
            for (int j = 0; j < 8; j++) {
                aA[j] = bf2f((unsigned short)voA[j]) + mA0 * bf2f((unsigned short)v0A[j])
                                                     + mA1 * bf2f((unsigned short)v1A[j]);
                aB[j] = bf2f((unsigned short)voB[j]) + mB0 * bf2f((unsigned short)v0B[j])
                                                     + mB1 * bf2f((unsigned short)v1B[j]);
            }
            if (!skip) {
                for (int k = 2; k < dA; k++) {
                    int kk = oA + k;
                    int sid = (kk < WCAP) ? s_win[kk] : slots[loA + k];
                    s16x8 vk = *(const s16x8*)&src[sid * SK + c8];
#pragma unroll
                    for (int j = 0; j < 8; j++) aA[j] += bf2f((unsigned short)vk[j]);
                }
                for (int k = 2; k < dB; k++) {
                    int kk = oB + k;
                    int sid = (kk < WCAP) ? s_win[kk] : slots[loB + k];
                    s16x8 vk = *(const s16x8*)&src[sid * SK + c8];
#pragma unroll
                    for (int j = 0; j < 8; j++) aB[j] += bf2f((unsigned short)vk[j]);
                }
                if (!L0) {
                    float cntA = (float)(dA + 1), cntB = (float)(dB + 1);
#pragma unroll
                    for (int j = 0; j < 8; j++) {
                        aA[j] = aA[j] * sc[j] + cntA * sh[j];
                        aB[j] = aB[j] * sc[j] + cntB * sh[j];
                    }
                }
            } else {
#pragma unroll
                for (int j = 0; j < 8; j++) { aA[j] = 0.f; aB[j] = 0.f; }
            }
            union { s16x8 v; unsigned short u[8]; } pkA, pkB;
#pragma unroll
            for (int j = 0; j < 8; j++) { pkA.u[j] = f2bf(aA[j]); pkB.u[j] = f2bf(aB[j]); }
            *(s16x8*)&Xs[rA * 128 + (c8 ^ ((rA & 7) << 3))] = pkA.v;
            *(s16x8*)&Xs[rB * 128 + (c8 ^ ((rB & 7) << 3))] = pkB.v;
        }

        s16x8 w1f[4];
        float bs1;
#pragma unroll
        for (int ks = 0; ks < KS1; ks++)
            w1f[ks] = *(const s16x8*)&wt1[colbase * 128 + ks * 32 + (lane >> 4) * 8];
        bs1 = b1[colbase];

        __syncthreads();

        f32x4 acc[4];
#pragma unroll
        for (int rb = 0; rb < 4; rb++) acc[rb] = 0;
#pragma unroll
        for (int ks = 0; ks < KS1; ks++) {
            int lk = ks * 32 + (lane >> 4) * 8;
            s16x8 af[4];
#pragma unroll
            for (int rb = 0; rb < 4; rb++) {
                int r = rb * 16 + (lane & 15);
                af[rb] = *(const s16x8*)&Xs[r * 128 + (lk ^ ((r & 7) << 3))];
            }
#pragma unroll
            for (int rb = 0; rb < 4; rb++)
                acc[rb] = __builtin_amdgcn_mfma_f32_16x16x32_bf16(af[rb], w1f[ks], acc[rb], 0, 0, 0);
        }

        __syncthreads();

#pragma unroll
        for (int rb = 0; rb < 4; rb++) {
#pragma unroll
            for (int reg = 0; reg < 4; reg++) {
                int row = rb * 16 + (lane >> 4) * 4 + reg;
                float v = fmaxf(acc[rb][reg] + bs1, 0.f);
                Xs[row * 128 + (colbase ^ ((row & 7) << 3))] = f2bf(v);
            }
        }

        s16x8 w2f[4];
        float bs2;
#pragma unroll
        for (int ks = 0; ks < 4; ks++)
            w2f[ks] = *(const s16x8*)&wt2[colbase * 128 + ks * 32 + (lane >> 4) * 8];
        bs2 = b2[colbase];

        __syncthreads();

#pragma unroll
        for (int rb = 0; rb < 4; rb++) acc[rb] = 0;
#pragma unroll
        for (int ks = 0; ks < 4; ks++) {
            int lk = ks * 32 + (lane >> 4) * 8;
            s16x8 af[4];
#pragma unroll
            for (int rb = 0; rb < 4; rb++) {
                int r = rb * 16 + (lane & 15);
                af[rb] = *(const s16x8*)&Xs[r * 128 + (lk ^ ((r & 7) << 3))];
            }
#pragma unroll
            for (int rb = 0; rb < 4; rb++)
                acc[rb] = __builtin_amdgcn_mfma_f32_16x16x32_bf16(af[rb], w2f[ks], acc[rb], 0, 0, 0);
        }

        float ps = 0.f, pq = 0.f;
#pragma unroll
        for (int rb = 0; rb < 4; rb++) {
#pragma unroll
            for (int reg = 0; reg < 4; reg++) {
                int row = rowBase + rb * 16 + (lane >> 4) * 4 + reg;
                float v = fmaxf(acc[rb][reg] + bs2, 0.f);
                unsigned short ub = f2bf(v);
                out[row * DD + colbase] = ub;
                float vb = bf2f(ub);
                ps += vb;
                pq += vb * vb;
            }
        }
        ps += __shfl_xor(ps, 16); ps += __shfl_xor(ps, 32);
        pq += __shfl_xor(pq, 16); pq += __shfl_xor(pq, 32);
        if (lane < 16) {
            partials[(long long)tile * 256 + colbase] = ps;
            partials[(long long)tile * 256 + 128 + colbase] = pq;
        }
        __syncthreads();   // all Xs/s_win reads done before next tile's staging
    }
}

// ---------- reduce BN partials + (last block) finalize scale/shift ----------
__global__ __launch_bounds__(256) void bn_red2_fin_kernel(
    const float* __restrict__ partials, float* __restrict__ sums, int* __restrict__ done,
    const float* __restrict__ gamma, const float* __restrict__ beta, float* __restrict__ ss) {
    float s = 0.f;
    for (int b = blockIdx.x; b < NBLK; b += gridDim.x)
        s += partials[(long long)b * 256 + threadIdx.x];
    atomicAdd(&sums[threadIdx.x], s);
    __threadfence();
    __syncthreads();
    __shared__ int tick;
    if (threadIdx.x == 0) tick = atomicAdd(done, 1);
    __syncthreads();
    if (tick == (int)gridDim.x - 1 && threadIdx.x < 128) {
        int c = threadIdx.x;
        float s0 = atomicAdd(&sums[c], 0.f);        // coherent read
        float s1 = atomicAdd(&sums[DD + c], 0.f);
        float mu = s0 / (float)NN;
        float var = s1 / (float)NN - mu * mu;
        float sc = gamma[c] * rsqrtf(var + BN_EPS);
        ss[c] = sc;
        ss[DD + c] = beta[c] - mu * sc;
    }
}

// ---------- per-graph max pool, vectorized s16x8 loads (16 threads/row, 16 rows) ----------
__global__ __launch_bounds__(256) void pool_kernel(const unsigned short* __restrict__ hm,
                                                   const float* __restrict__ ss,
                                                   const int* __restrict__ start,
                                                   float* __restrict__ pooled, int l) {
    __shared__ float red[16][128];
    int g = blockIdx.x;
    int rp = threadIdx.x >> 4;          // 0..15 rows in flight
    int c8 = (threadIdx.x & 15) * 8;
    int lo = start[g], hi = start[g + 1];
    float sc[8], sh[8];
#pragma unroll
    for (int j = 0; j < 8; j++) { sc[j] = ss[c8 + j]; sh[j] = ss[DD + c8 + j]; }
    float m[8];
#pragma unroll
    for (int j = 0; j < 8; j++) m[j] = -FLT_MAX;
    for (int n = lo + rp; n < hi; n += 16) {
        s16x8 v = *(const s16x8*)&hm[(long long)n * DD + c8];
#pragma unroll
        for (int j = 0; j < 8; j++)
            m[j] = fmaxf(m[j], bf2f((unsigned short)v[j]) * sc[j] + sh[j]);
    }
#pragma unroll
    for (int j = 0; j < 8; j++) red[rp][c8 + j] = m[j];
    __syncthreads();
    if (threadIdx.x < 128) {
        int c = threadIdx.x;
        float mm = red[0][c];
#pragma unroll
        for (int r = 1; r < 16; r++) mm = fmaxf(mm, red[r][c]);
        pooled[(long long)g * (3 * DD) + l * DD + c] = mm;
    }
}

// ---------- final: out = relu(pooled @ w_emb + b_emb) ----------
__global__ __launch_bounds__(256) void emb_kernel(const float* __restrict__ pooled,
                                                  const float* __restrict__ w,
                                                  const float* __restrict__ b,
                                                  float* __restrict__ out) {
    __shared__ float pl[8][384];
    int tid = threadIdx.x;
    int g0 = blockIdx.x * 8;
#pragma unroll
    for (int i = 0; i < 12; i++) {
        int idx = tid + i * 256;
        int gg = idx / 384, c = idx % 384;
        pl[gg][c] = pooled[(long long)(g0 + gg) * 384 + c];
    }
    __syncthreads();
    float acc[8];
#pragma unroll
    for (int gg = 0; gg < 8; gg++) acc[gg] = 0.f;
    for (int k = 0; k < 384; k++) {
        float wv = w[k * 256 + tid];
#pragma unroll
        for (int gg = 0; gg < 8; gg++) acc[gg] += pl[gg][k] * wv;
    }
    float bb = b[tid];
#pragma unroll
    for (int gg = 0; gg < 8; gg++)
        out[(long long)(g0 + gg) * 256 + tid] = fmaxf(acc[gg] + bb, 0.f);
}

extern "C" void kernel_launch(void* const* d_in, const int* in_sizes, int n_in,
                              void* d_out, int out_size, void* d_ws, size_t ws_size,
                              hipStream_t stream) {
    const float* x = (const float*)d_in[0];
    const void* eidx = d_in[1];
    const void* batch = d_in[2];
    const float* w1[3] = { (const float*)d_in[3],  (const float*)d_in[9],  (const float*)d_in[15] };
    const float* b1[3] = { (const float*)d_in[4],  (const float*)d_in[10], (const float*)d_in[16] };
    const float* w2[3] = { (const float*)d_in[5],  (const float*)d_in[11], (const float*)d_in[17] };
    const float* b2[3] = { (const float*)d_in[6],  (const float*)d_in[12], (const float*)d_in[18] };
    const float* gm[3] = { (const float*)d_in[7],  (const float*)d_in[13], (const float*)d_in[19] };
    const float* bt[3] = { (const float*)d_in[8],  (const float*)d_in[14], (const float*)d_in[20] };
    const float* w_emb = (const float*)d_in[21];
    const float* b_emb = (const float*)d_in[22];
    float* out = (float*)d_out;

    // workspace: two ping-pong h buffers (R1 doubles as xb [N,96])
    unsigned short* R1 = (unsigned short*)d_ws;              // NN*128 u16
    unsigned short* R2 = R1 + (size_t)NN * DD;               // NN*128 u16
    float* pooled = (float*)(R2 + (size_t)NN * DD);          // NG*384
    float* partials = pooled + (size_t)NG * 384;             // NBLK*256
    unsigned short* wtb = (unsigned short*)(partials + (size_t)NBLK * 256); // 6*16384
    float* ss = (float*)(wtb + 6 * 16384);                   // 3*256
    // ---- zeroed region (one memset): sums[3*256] + done[8] + deg[NN] ----
    float* sums = ss + 3 * 256;                              // 3*256
    int* done = (int*)(sums + 3 * 256);                      // 8
    int* deg = done + 8;                                     // NN
    size_t zbytes = (3 * 256) * sizeof(float) + 8 * sizeof(int) + (size_t)NN * sizeof(int);
    // ---- rest ----
    int* incl = deg + NN;                                    // NN
    int* bsum = incl + NN;                                   // NB_SCAN
    int* rowptr = bsum + NB_SCAN;                            // NN+1
    int* cursor = rowptr + NN + 1;                           // NN
    int* slots = cursor + NN;                                // NE
    int* start = slots + NE;                                 // NG+1
    int* flags = start + NG + 1;                             // 2

    // zero sums + done + deg (DMA op, must precede prep's count atomics)
    hipMemsetAsync(sums, 0, zbytes, stream);

    // prep: gs + count + xconv + wconv + detect — one launch
    prep_kernel<<<GS_BLKS + CNT_BLKS + XCONV_BLKS + WCONV_BLKS + 1, 256, 0, stream>>>(
        x, R1, w1[0], w2[0], w1[1], w2[1], w1[2], w2[2], wtb,
        eidx, batch, start, deg, flags);

    scan1_kernel<<<NB_SCAN, 256, 0, stream>>>(deg, incl, bsum);
    scan23_kernel<<<NB_SCAN, 256, 0, stream>>>(incl, deg, bsum, rowptr, cursor);
    fill_kernel<<<(NE + 255) / 256, 256, 0, stream>>>(eidx, flags, cursor, slots);

    // layer 0: R1(xb) -> R2 ; layer 1: R2 -> R1 ; layer 2: R1 -> R2
    unsigned short* hin[3] = { R1, R2, R1 };
    unsigned short* hout[3] = { R2, R1, R2 };
    for (int l = 0; l < 3; l++) {
        const unsigned short* wt1 = wtb + l * 2 * 16384;
        const unsigned short* wt2 = wt1 + 16384;
        float* ss_l = ss + l * 256;
        if (l == 0)
            fused_layer<1><<<PGRID, 512, 0, stream>>>(hin[l], nullptr, rowptr, slots, wt1, wt2,
                                                      b1[l], b2[l], hout[l], partials);
        else
            fused_layer<0><<<PGRID, 512, 0, stream>>>(hin[l], ss + (l - 1) * 256, rowptr, slots,
                                                      wt1, wt2, b1[l], b2[l], hout[l], partials);
        bn_red2_fin_kernel<<<256, 256, 0, stream>>>(partials, sums + l * 256, done + l,
                                                    gm[l], bt[l], ss_l);
        pool_kernel<<<NG, 256, 0, stream>>>(hout[l], ss_l, start, pooled, l);
    }
    emb_kernel<<<NG / 8, 256, 0, stream>>>(pooled, w_emb, b_emb, out);
}

// Round 17
// 350.315 us; speedup vs baseline: 1.4576x; 1.4576x over previous
//
#include <hip/hip_runtime.h>
#include <hip/hip_bf16.h>
#include <float.h>

#define NN 200000
#define NE 400000
#define NG 4096
#define FIN 77
#define DD 128
#define BN_EPS 1e-5f
#define NB_SCAN ((NN + 255) / 256)   // 782
#define NBLK (NN / 64)               // 3125 fused blocks
#define WCAP 1024                    // LDS slot-window capacity

// prep role ranges
#define GS_BLKS 17
#define CNT_BLKS ((NE + 255) / 256)  // 1563
#define XCONV_BLKS (NN * 12 / 256)   // 9375
#define WCONV_BLKS 192

typedef float f32x4 __attribute__((ext_vector_type(4)));
typedef short s16x8 __attribute__((ext_vector_type(8)));

__device__ __forceinline__ unsigned short f2bf(float x) {
    unsigned b = __float_as_uint(x);
    unsigned r = (b + 0x7FFFu + ((b >> 16) & 1u)) >> 16;
    return (unsigned short)r;
}
__device__ __forceinline__ float bf2f(unsigned short u) {
    return __uint_as_float(((unsigned)u) << 16);
}

__device__ __forceinline__ int load_idx(const void* p, int is64, long long i) {
    return is64 ? (int)((const long long*)p)[i] : ((const int*)p)[i];
}

// ---------- prep: graph_starts + degree count + xconv + wconv + detect (one launch) ----------
__global__ __launch_bounds__(256) void prep_kernel(
    const float* __restrict__ x, unsigned short* __restrict__ xb,
    const float* __restrict__ w10, const float* __restrict__ w20,
    const float* __restrict__ w11, const float* __restrict__ w21,
    const float* __restrict__ w12, const float* __restrict__ w22,
    unsigned short* __restrict__ wtb,
    const void* __restrict__ eidx, const void* __restrict__ batch,
    int* __restrict__ start, int* __restrict__ deg, int* __restrict__ flags)
{
    int b = blockIdx.x;
    if (b < GS_BLKS) {
        __shared__ int sb64;
        if (threadIdx.x == 0) {
            int b64 = 1;
            const unsigned* bw = (const unsigned*)batch;
            for (int i = 0; i < 16; i++) if (bw[NN - 1 - 2 * i] != 0u) b64 = 0;
            sb64 = b64;
        }
        __syncthreads();
        int is64 = sb64;
        int g = b * 256 + threadIdx.x;
        if (g > NG) return;
        int lo = 0, hi = NN;
        while (lo < hi) {
            int mid = (lo + hi) >> 1;
            int v = load_idx(batch, is64, mid);
            if (v < g) lo = mid + 1; else hi = mid;
        }
        start[g] = lo;
    } else if (b < GS_BLKS + CNT_BLKS) {
        __shared__ int se64;
        if (threadIdx.x == 0) {
            int e64 = 1;
            const unsigned* ew = (const unsigned*)eidx;
            for (int i = 0; i < 16; i++) if (ew[2 * NE - 1 - 2 * i] != 0u) e64 = 0;
            se64 = e64;
        }
        __syncthreads();
        int e = (b - GS_BLKS) * 256 + threadIdx.x;
        if (e >= NE) return;
        int dst = load_idx(eidx, se64, (long long)NE + e);
        atomicAdd(&deg[dst], 1);
    } else if (b < GS_BLKS + CNT_BLKS + XCONV_BLKS) {
        int idx = (b - GS_BLKS - CNT_BLKS) * 256 + threadIdx.x;
        int row = idx / 12, c8 = (idx % 12) * 8;
        union { s16x8 v; unsigned short u[8]; } pk;
#pragma unroll
        for (int j = 0; j < 8; j++) {
            int c = c8 + j;
            pk.u[j] = (c < FIN) ? f2bf(x[(long long)row * FIN + c]) : (unsigned short)0;
        }
        *(s16x8*)&xb[(long long)row * 96 + c8] = pk.v;
    } else if (b < GS_BLKS + CNT_BLKS + XCONV_BLKS + WCONV_BLKS) {
        int bb = b - GS_BLKS - CNT_BLKS - XCONV_BLKS;
        int l = bb >> 6;
        int idx = (bb & 63) * 256 + threadIdx.x;
        int c = idx >> 7, k = idx & 127;
        const float* w1 = (l == 0) ? w10 : ((l == 1) ? w11 : w12);
        const float* w2 = (l == 0) ? w20 : ((l == 1) ? w21 : w22);
        int K1 = (l == 0) ? FIN : DD;
        unsigned short* wt1 = wtb + l * 2 * 16384;
        wt1[idx] = f2bf(k < K1 ? w1[k * DD + c] : 0.f);
        wt1[16384 + idx] = f2bf(w2[k * DD + c]);
    } else {
        if (threadIdx.x == 0) {
            int e64 = 1, b64 = 1;
            const unsigned* ew = (const unsigned*)eidx;
            const unsigned* bw = (const unsigned*)batch;
            for (int i = 0; i < 16; i++) {
                if (ew[2 * NE - 1 - 2 * i] != 0u) e64 = 0;
                if (bw[NN - 1 - 2 * i] != 0u) b64 = 0;
            }
            flags[0] = e64;
            flags[1] = b64;
        }
    }
}

__global__ void scan1_kernel(const int* __restrict__ deg, int* __restrict__ incl,
                             int* __restrict__ bsum) {
    __shared__ int sh[256];
    int i = blockIdx.x * 256 + threadIdx.x;
    int v = (i < NN) ? deg[i] : 0;
    sh[threadIdx.x] = v;
    __syncthreads();
    for (int off = 1; off < 256; off <<= 1) {
        int t = (threadIdx.x >= off) ? sh[threadIdx.x - off] : 0;
        __syncthreads();
        sh[threadIdx.x] += t;
        __syncthreads();
    }
    if (i < NN) incl[i] = sh[threadIdx.x];
    if (threadIdx.x == 255) bsum[blockIdx.x] = sh[255];
}

// scan2+scan3 merged: each block re-sums bsum[0..b) itself (<=782 ints, cheap)
__global__ __launch_bounds__(256) void scan23_kernel(
    const int* __restrict__ incl, const int* __restrict__ deg,
    const int* __restrict__ bsum, int* __restrict__ rowptr, int* __restrict__ cursor) {
    __shared__ int red[256];
    int b = blockIdx.x;
    int t = threadIdx.x;
    int s = 0;
    for (int i = t; i < b; i += 256) s += bsum[i];
    red[t] = s;
    __syncthreads();
    for (int off = 128; off > 0; off >>= 1) {
        if (t < off) red[t] += red[t + off];
        __syncthreads();
    }
    int pfx = red[0];
    int i = b * 256 + t;
    if (i < NN) {
        int ex = pfx + incl[i] - deg[i];
        rowptr[i] = ex;
        cursor[i] = ex;
    }
    if (i == 0) rowptr[NN] = NE;
}

__global__ void fill_kernel(const void* __restrict__ eidx, const int* __restrict__ flags,
                            int* __restrict__ cursor, int* __restrict__ slots) {
    int e = blockIdx.x * 256 + threadIdx.x;
    if (e >= NE) return;
    int is64 = flags[0];
    int src = load_idx(eidx, is64, e);
    int dst = load_idx(eidx, is64, (long long)NE + e);
    int pos = atomicAdd(&cursor[dst], 1);
    slots[pos] = src;
}

// ---------- fused layer: gather(+BN affine) -> GEMM1 -> GEMM2 -> h + BN partials ----------
template <int L0>
__global__ __launch_bounds__(512, 8) void fused_layer(
    const unsigned short* __restrict__ src, const float* __restrict__ ss,
    const int* __restrict__ rowptr, const int* __restrict__ slots,
    const unsigned short* __restrict__ wt1, const unsigned short* __restrict__ wt2,
    const float* __restrict__ b1, const float* __restrict__ b2,
    unsigned short* __restrict__ out, float* __restrict__ partials)
{
    __shared__ unsigned short Xs[64 * 128];
    __shared__ int s_lo[65];
    __shared__ int s_win[WCAP];
    constexpr int SK = L0 ? 96 : 128;
    constexpr int KS1 = L0 ? 3 : 4;
    int tid = threadIdx.x;
    int lane = tid & 63;
    int w = tid >> 6;                 // 0..7
    int rowBase = blockIdx.x * 64;

    int wb = rowptr[rowBase];
    int wn = rowptr[rowBase + 64] - wb;
    if (tid < 65) s_lo[tid] = rowptr[rowBase + tid];
    int wcap = (wn < WCAP) ? wn : WCAP;
    for (int i = tid; i < wcap; i += 512) s_win[i] = slots[wb + i];
    __syncthreads();

    {
        int rp = tid >> 4;            // 0..31
        int c8 = (tid & 15) * 8;
        float sc[8], sh[8];
        if (!L0) {
#pragma unroll
            for (int j = 0; j < 8; j++) { sc[j] = ss[c8 + j]; sh[j] = ss[DD + c8 + j]; }
        }
        int rA = rp, rB = 32 + rp;
        int griA = rowBase + rA, griB = rowBase + rB;
        bool skip = (L0 && c8 >= 96);
        s16x8 voA = {}, v0A = {}, v1A = {}, voB = {}, v0B = {}, v1B = {};
        int dA = 0, dB = 0, loA = 0, loB = 0, oA = 0, oB = 0;
        float mA0 = 0.f, mA1 = 0.f, mB0 = 0.f, mB1 = 0.f;
        if (!skip) {
            loA = s_lo[rA]; dA = s_lo[rA + 1] - loA; oA = loA - wb;
            loB = s_lo[rB]; dB = s_lo[rB + 1] - loB; oB = loB - wb;
            int iA0 = (dA > 0) ? ((oA < WCAP) ? s_win[oA] : slots[loA]) : griA;
            int iA1 = (dA > 1) ? ((oA + 1 < WCAP) ? s_win[oA + 1] : slots[loA + 1]) : griA;
            int iB0 = (dB > 0) ? ((oB < WCAP) ? s_win[oB] : slots[loB]) : griB;
            int iB1 = (dB > 1) ? ((oB + 1 < WCAP) ? s_win[oB + 1] : slots[loB + 1]) : griB;
            voA = *(const s16x8*)&src[griA * SK + c8];
            v0A = *(const s16x8*)&src[iA0 * SK + c8];
            v1A = *(const s16x8*)&src[iA1 * SK + c8];
            voB = *(const s16x8*)&src[griB * SK + c8];
            v0B = *(const s16x8*)&src[iB0 * SK + c8];
            v1B = *(const s16x8*)&src[iB1 * SK + c8];
            mA0 = (dA > 0) ? 1.f : 0.f; mA1 = (dA > 1) ? 1.f : 0.f;
            mB0 = (dB > 0) ? 1.f : 0.f; mB1 = (dB > 1) ? 1.f : 0.f;
        }
        float aA[8], aB[8];
#pragma unroll
        for (int j = 0; j < 8; j++) {
            aA[j] = bf2f((unsigned short)voA[j]) + mA0 * bf2f((unsigned short)v0A[j])
                                                 + mA1 * bf2f((unsigned short)v1A[j]);
            aB[j] = bf2f((unsigned short)voB[j]) + mB0 * bf2f((unsigned short)v0B[j])
                                                 + mB1 * bf2f((unsigned short)v1B[j]);
        }
        if (!skip) {
            for (int k = 2; k < dA; k++) {
                int kk = oA + k;
                int sid = (kk < WCAP) ? s_win[kk] : slots[loA + k];
                s16x8 vk = *(const s16x8*)&src[sid * SK + c8];
#pragma unroll
                for (int j = 0; j < 8; j++) aA[j] += bf2f((unsigned short)vk[j]);
            }
            for (int k = 2; k < dB; k++) {
                int kk = oB + k;
                int sid = (kk < WCAP) ? s_win[kk] : slots[loB + k];
                s16x8 vk = *(const s16x8*)&src[sid * SK + c8];
#pragma unroll
                for (int j = 0; j < 8; j++) aB[j] += bf2f((unsigned short)vk[j]);
            }
            if (!L0) {
                float cntA = (float)(dA + 1), cntB = (float)(dB + 1);
#pragma unroll
                for (int j = 0; j < 8; j++) {
                    aA[j] = aA[j] * sc[j] + cntA * sh[j];
                    aB[j] = aB[j] * sc[j] + cntB * sh[j];
                }
            }
        } else {
#pragma unroll
            for (int j = 0; j < 8; j++) { aA[j] = 0.f; aB[j] = 0.f; }
        }
        union { s16x8 v; unsigned short u[8]; } pkA, pkB;
#pragma unroll
        for (int j = 0; j < 8; j++) { pkA.u[j] = f2bf(aA[j]); pkB.u[j] = f2bf(aB[j]); }
        *(s16x8*)&Xs[rA * 128 + (c8 ^ ((rA & 7) << 3))] = pkA.v;
        *(s16x8*)&Xs[rB * 128 + (c8 ^ ((rB & 7) << 3))] = pkB.v;
    }

    int colbase = w * 16 + (lane & 15);
    s16x8 w1f[4];
    float bs1;
#pragma unroll
    for (int ks = 0; ks < KS1; ks++)
        w1f[ks] = *(const s16x8*)&wt1[colbase * 128 + ks * 32 + (lane >> 4) * 8];
    bs1 = b1[colbase];

    __syncthreads();

    f32x4 acc[4];
#pragma unroll
    for (int rb = 0; rb < 4; rb++) acc[rb] = 0;
#pragma unroll
    for (int ks = 0; ks < KS1; ks++) {
        int lk = ks * 32 + (lane >> 4) * 8;
        s16x8 af[4];
#pragma unroll
        for (int rb = 0; rb < 4; rb++) {
            int r = rb * 16 + (lane & 15);
            af[rb] = *(const s16x8*)&Xs[r * 128 + (lk ^ ((r & 7) << 3))];
        }
#pragma unroll
        for (int rb = 0; rb < 4; rb++)
            acc[rb] = __builtin_amdgcn_mfma_f32_16x16x32_bf16(af[rb], w1f[ks], acc[rb], 0, 0, 0);
    }

    __syncthreads();

#pragma unroll
    for (int rb = 0; rb < 4; rb++) {
#pragma unroll
        for (int reg = 0; reg < 4; reg++) {
            int row = rb * 16 + (lane >> 4) * 4 + reg;
            float v = fmaxf(acc[rb][reg] + bs1, 0.f);
            Xs[row * 128 + (colbase ^ ((row & 7) << 3))] = f2bf(v);
        }
    }

    s16x8 w2f[4];
    float bs2;
#pragma unroll
    for (int ks = 0; ks < 4; ks++)
        w2f[ks] = *(const s16x8*)&wt2[colbase * 128 + ks * 32 + (lane >> 4) * 8];
    bs2 = b2[colbase];

    __syncthreads();

#pragma unroll
    for (int rb = 0; rb < 4; rb++) acc[rb] = 0;
#pragma unroll
    for (int ks = 0; ks < 4; ks++) {
        int lk = ks * 32 + (lane >> 4) * 8;
        s16x8 af[4];
#pragma unroll
        for (int rb = 0; rb < 4; rb++) {
            int r = rb * 16 + (lane & 15);
            af[rb] = *(const s16x8*)&Xs[r * 128 + (lk ^ ((r & 7) << 3))];
        }
#pragma unroll
        for (int rb = 0; rb < 4; rb++)
            acc[rb] = __builtin_amdgcn_mfma_f32_16x16x32_bf16(af[rb], w2f[ks], acc[rb], 0, 0, 0);
    }

    float ps = 0.f, pq = 0.f;
#pragma unroll
    for (int rb = 0; rb < 4; rb++) {
#pragma unroll
        for (int reg = 0; reg < 4; reg++) {
            int row = rowBase + rb * 16 + (lane >> 4) * 4 + reg;
            float v = fmaxf(acc[rb][reg] + bs2, 0.f);
            unsigned short ub = f2bf(v);
            out[row * DD + colbase] = ub;
            float vb = bf2f(ub);
            ps += vb;
            pq += vb * vb;
        }
    }
    ps += __shfl_xor(ps, 16); ps += __shfl_xor(ps, 32);
    pq += __shfl_xor(pq, 16); pq += __shfl_xor(pq, 32);
    if (lane < 16) {
        partials[(long long)blockIdx.x * 256 + colbase] = ps;
        partials[(long long)blockIdx.x * 256 + 128 + colbase] = pq;
    }
}

// ---------- reduce BN partials + (last block) finalize scale/shift ----------
__global__ __launch_bounds__(256) void bn_red2_fin_kernel(
    const float* __restrict__ partials, float* __restrict__ sums, int* __restrict__ done,
    const float* __restrict__ gamma, const float* __restrict__ beta, float* __restrict__ ss) {
    float s = 0.f;
    for (int b = blockIdx.x; b < NBLK; b += gridDim.x)
        s += partials[(long long)b * 256 + threadIdx.x];
    atomicAdd(&sums[threadIdx.x], s);
    __threadfence();
    __syncthreads();
    __shared__ int tick;
    if (threadIdx.x == 0) tick = atomicAdd(done, 1);
    __syncthreads();
    if (tick == (int)gridDim.x - 1 && threadIdx.x < 128) {
        int c = threadIdx.x;
        float s0 = atomicAdd(&sums[c], 0.f);        // coherent read
        float s1 = atomicAdd(&sums[DD + c], 0.f);
        float mu = s0 / (float)NN;
        float var = s1 / (float)NN - mu * mu;
        float sc = gamma[c] * rsqrtf(var + BN_EPS);
        ss[c] = sc;
        ss[DD + c] = beta[c] - mu * sc;
    }
}

// ---------- per-graph max pool, vectorized s16x8 loads (16 threads/row, 16 rows) ----------
__global__ __launch_bounds__(256) void pool_kernel(const unsigned short* __restrict__ hm,
                                                   const float* __restrict__ ss,
                                                   const int* __restrict__ start,
                                                   float* __restrict__ pooled, int l) {
    __shared__ float red[16][128];
    int g = blockIdx.x;
    int rp = threadIdx.x >> 4;          // 0..15 rows in flight
    int c8 = (threadIdx.x & 15) * 8;
    int lo = start[g], hi = start[g + 1];
    float sc[8], sh[8];
#pragma unroll
    for (int j = 0; j < 8; j++) { sc[j] = ss[c8 + j]; sh[j] = ss[DD + c8 + j]; }
    float m[8];
#pragma unroll
    for (int j = 0; j < 8; j++) m[j] = -FLT_MAX;
    for (int n = lo + rp; n < hi; n += 16) {
        s16x8 v = *(const s16x8*)&hm[(long long)n * DD + c8];
#pragma unroll
        for (int j = 0; j < 8; j++)
            m[j] = fmaxf(m[j], bf2f((unsigned short)v[j]) * sc[j] + sh[j]);
    }
#pragma unroll
    for (int j = 0; j < 8; j++) red[rp][c8 + j] = m[j];
    __syncthreads();
    if (threadIdx.x < 128) {
        int c = threadIdx.x;
        float mm = red[0][c];
#pragma unroll
        for (int r = 1; r < 16; r++) mm = fmaxf(mm, red[r][c]);
        pooled[(long long)g * (3 * DD) + l * DD + c] = mm;
    }
}

// ---------- final: out = relu(pooled @ w_emb + b_emb) ----------
__global__ __launch_bounds__(256) void emb_kernel(const float* __restrict__ pooled,
                                                  const float* __restrict__ w,
                                                  const float* __restrict__ b,
                                                  float* __restrict__ out) {
    __shared__ float pl[8][384];
    int tid = threadIdx.x;
    int g0 = blockIdx.x * 8;
#pragma unroll
    for (int i = 0; i < 12; i++) {
        int idx = tid + i * 256;
        int gg = idx / 384, c = idx % 384;
        pl[gg][c] = pooled[(long long)(g0 + gg) * 384 + c];
    }
    __syncthreads();
    float acc[8];
#pragma unroll
    for (int gg = 0; gg < 8; gg++) acc[gg] = 0.f;
    for (int k = 0; k < 384; k++) {
        float wv = w[k * 256 + tid];
#pragma unroll
        for (int gg = 0; gg < 8; gg++) acc[gg] += pl[gg][k] * wv;
    }
    float bb = b[tid];
#pragma unroll
    for (int gg = 0; gg < 8; gg++)
        out[(long long)(g0 + gg) * 256 + tid] = fmaxf(acc[gg] + bb, 0.f);
}

extern "C" void kernel_launch(void* const* d_in, const int* in_sizes, int n_in,
                              void* d_out, int out_size, void* d_ws, size_t ws_size,
                              hipStream_t stream) {
    const float* x = (const float*)d_in[0];
    const void* eidx = d_in[1];
    const void* batch = d_in[2];
    const float* w1[3] = { (const float*)d_in[3],  (const float*)d_in[9],  (const float*)d_in[15] };
    const float* b1[3] = { (const float*)d_in[4],  (const float*)d_in[10], (const float*)d_in[16] };
    const float* w2[3] = { (const float*)d_in[5],  (const float*)d_in[11], (const float*)d_in[17] };
    const float* b2[3] = { (const float*)d_in[6],  (const float*)d_in[12], (const float*)d_in[18] };
    const float* gm[3] = { (const float*)d_in[7],  (const float*)d_in[13], (const float*)d_in[19] };
    const float* bt[3] = { (const float*)d_in[8],  (const float*)d_in[14], (const float*)d_in[20] };
    const float* w_emb = (const float*)d_in[21];
    const float* b_emb = (const float*)d_in[22];
    float* out = (float*)d_out;

    // workspace: two ping-pong h buffers (R1 doubles as xb [N,96])
    unsigned short* R1 = (unsigned short*)d_ws;              // NN*128 u16
    unsigned short* R2 = R1 + (size_t)NN * DD;               // NN*128 u16
    float* pooled = (float*)(R2 + (size_t)NN * DD);          // NG*384
    float* partials = pooled + (size_t)NG * 384;             // NBLK*256
    unsigned short* wtb = (unsigned short*)(partials + (size_t)NBLK * 256); // 6*16384
    float* ss = (float*)(wtb + 6 * 16384);                   // 3*256
    // ---- zeroed region (one memset): sums[3*256] + done[8] + deg[NN] ----
    float* sums = ss + 3 * 256;                              // 3*256
    int* done = (int*)(sums + 3 * 256);                      // 8
    int* deg = done + 8;                                     // NN
    size_t zbytes = (3 * 256) * sizeof(float) + 8 * sizeof(int) + (size_t)NN * sizeof(int);
    // ---- rest ----
    int* incl = deg + NN;                                    // NN
    int* bsum = incl + NN;                                   // NB_SCAN
    int* rowptr = bsum + NB_SCAN;                            // NN+1
    int* cursor = rowptr + NN + 1;                           // NN
    int* slots = cursor + NN;                                // NE
    int* start = slots + NE;                                 // NG+1
    int* flags = start + NG + 1;                             // 2

    // zero sums + done + deg (DMA op, must precede prep's count atomics)
    hipMemsetAsync(sums, 0, zbytes, stream);

    // prep: gs + count + xconv + wconv + detect — one launch
    prep_kernel<<<GS_BLKS + CNT_BLKS + XCONV_BLKS + WCONV_BLKS + 1, 256, 0, stream>>>(
        x, R1, w1[0], w2[0], w1[1], w2[1], w1[2], w2[2], wtb,
        eidx, batch, start, deg, flags);

    scan1_kernel<<<NB_SCAN, 256, 0, stream>>>(deg, incl, bsum);
    scan23_kernel<<<NB_SCAN, 256, 0, stream>>>(incl, deg, bsum, rowptr, cursor);
    fill_kernel<<<(NE + 255) / 256, 256, 0, stream>>>(eidx, flags, cursor, slots);

    // layer 0: R1(xb) -> R2 ; layer 1: R2 -> R1 ; layer 2: R1 -> R2
    unsigned short* hin[3] = { R1, R2, R1 };
    unsigned short* hout[3] = { R2, R1, R2 };
    for (int l = 0; l < 3; l++) {
        const unsigned short* wt1 = wtb + l * 2 * 16384;
        const unsigned short* wt2 = wt1 + 16384;
        float* ss_l = ss + l * 256;
        if (l == 0)
            fused_layer<1><<<NBLK, 512, 0, stream>>>(hin[l], nullptr, rowptr, slots, wt1, wt2,
                                                     b1[l], b2[l], hout[l], partials);
        else
            fused_layer<0><<<NBLK, 512, 0, stream>>>(hin[l], ss + (l - 1) * 256, rowptr, slots,
                                                     wt1, wt2, b1[l], b2[l], hout[l], partials);
        bn_red2_fin_kernel<<<256, 256, 0, stream>>>(partials, sums + l * 256, done + l,
                                                    gm[l], bt[l], ss_l);
        pool_kernel<<<NG, 256, 0, stream>>>(hout[l], ss_l, start, pooled, l);
    }
    emb_kernel<<<NG / 8, 256, 0, stream>>>(pooled, w_emb, b_emb, out);
}